// Round 10
// baseline (49840.131 us; speedup 1.0000x reference)
//
#include <hip/hip_runtime.h>
#include <math.h>

#define NB   512
#define TENC 128
#define FDEC 32
#define TTOT 160
#define HD   512
#define HE   262144          // shorts per h buffer (512n x 512d)
#define NBLK 128

typedef short  short8  __attribute__((ext_vector_type(8)));
typedef float  f32x16  __attribute__((ext_vector_type(16)));

__device__ __forceinline__ unsigned short f2bf(float f) {
  unsigned u = __float_as_uint(f);
  u += 0x7FFFu + ((u >> 16) & 1u);          // RNE
  return (unsigned short)(u >> 16);
}
__device__ __forceinline__ float bf2f(unsigned short h) {
  return __uint_as_float(((unsigned)h) << 16);
}
__device__ __forceinline__ void gll16(const void* g, void* l) {
  __builtin_amdgcn_global_load_lds(
      (const __attribute__((address_space(1))) void*)g,
      (__attribute__((address_space(3))) void*)l, 16, 0, 0);
}

// packed-h short index for element (n, d): 32-row n-blocks, fragment-major.
// unit u = cks*64 + kq*32 + lanw ; cks=d>>4, kq=(d>>3)&1.  (k-chunks of 16)
__device__ __forceinline__ size_t hpk(int n, int d) {
  int nblk = n >> 5, lanw = n & 31;
  int cks = d >> 4, kq = (d >> 3) & 1;
  return (size_t)nblk * 16384 +
         (size_t)((((cks * 64 + kq * 32 + lanw) << 3) + (d & 7)));
}

// grid barrier: monotonic counter, device(agent)-scope release/acquire.
__device__ __forceinline__ void gridbar(unsigned* cnt, unsigned target) {
  __syncthreads();
  if (threadIdx.x == 0) {
    __hip_atomic_fetch_add(cnt, 1u, __ATOMIC_RELEASE, __HIP_MEMORY_SCOPE_AGENT);
    while (__hip_atomic_load(cnt, __ATOMIC_ACQUIRE, __HIP_MEMORY_SCOPE_AGENT) < target)
      __builtin_amdgcn_s_sleep(2);
  }
  __syncthreads();
}

// ---------------------------------------------------------------------------
// split weights hi/lo bf16 into fragment-major 32-j slices. j = d*4 + gate.
// W1p: 64 J x 2048 units (u = cks*64 + kgrp*32 + jl, cks<32), hi | lo(+16384)
// W2p: 64 J x 4096 units (cks<64, K = [Wih2 | Whh2]),         hi | lo(+32768)
// ---------------------------------------------------------------------------
__global__ __launch_bounds__(256) void split_w(
    const float* __restrict__ Whh1, const float* __restrict__ Wih2,
    const float* __restrict__ Whh2,
    unsigned short* __restrict__ W1p, unsigned short* __restrict__ W2p)
{
  int idx = blockIdx.x * 256 + threadIdx.x;
  if (idx < 131072) {                       // W1
    int J = idx >> 11, u = idx & 2047;
    int cks = u >> 6, kgrp = (u >> 5) & 1, jl = u & 31;
    int j = J * 32 + jl;
    int k = cks * 16 + kgrp * 8;
    int g = j & 3, dd = j >> 2;
    const float* s = Whh1 + (size_t)(g * HD + dd) * HD + k;
    unsigned short* oh = W1p + ((size_t)J << 15) + (size_t)u * 8;
    unsigned short* ol = oh + 16384;
#pragma unroll
    for (int i = 0; i < 8; ++i) {
      float v = s[i];
      unsigned short h = f2bf(v);
      oh[i] = h; ol[i] = f2bf(v - bf2f(h));
    }
  } else {                                  // W2
    int q2 = idx - 131072;
    if (q2 >= 262144) return;
    int J = q2 >> 12, u = q2 & 4095;
    int cks = u >> 6, kgrp = (u >> 5) & 1, jl = u & 31;
    int j = J * 32 + jl;
    int k = cks * 16 + kgrp * 8;
    int g = j & 3, dd = j >> 2;
    const float* s = (k < 512) ? Wih2 + (size_t)(g * HD + dd) * HD + k
                               : Whh2 + (size_t)(g * HD + dd) * HD + (k - 512);
    unsigned short* oh = W2p + ((size_t)J << 16) + (size_t)u * 8;
    unsigned short* ol = oh + 32768;
#pragma unroll
    for (int i = 0; i < 8; ++i) {
      float v = s[i];
      unsigned short h = f2bf(v);
      oh[i] = h; ol[i] = f2bf(v - bf2f(h));
    }
  }
}

// ---------------------------------------------------------------------------
// Persistent 2-layer LSTM. 128 blocks x 512 thr, 128KB LDS (1 block/CU).
// Blocks 0..63  (B1): W1 slice 32j resident; phase A: gates1+cell1 for all n.
// Blocks 64..127(B2): W2 slice 32j resident; phase B: gates2+cell2+FC.
// 2 grid barriers per step. Weights staged into LDS ONCE.
// ---------------------------------------------------------------------------
__global__ __launch_bounds__(512, 1) void lstm_persist(
    unsigned short* __restrict__ h1H, unsigned short* __restrict__ h1L,
    unsigned short* __restrict__ h2H, unsigned short* __restrict__ h2L,
    float* __restrict__ c1, float* __restrict__ c2,
    const unsigned short* __restrict__ W1p, const unsigned short* __restrict__ W2p,
    const float* __restrict__ Wih1,
    const float* __restrict__ bih1, const float* __restrict__ bhh1,
    const float* __restrict__ bih2, const float* __restrict__ bhh2,
    const float* __restrict__ x, const float* __restrict__ tgt,
    const int* __restrict__ tfm,
    const float* __restrict__ wfc, const float* __restrict__ bfc,
    float* __restrict__ outp, unsigned* __restrict__ cnt)
{
  __shared__ unsigned short Ws[65536];      // 128 KB, resident weight slice
  const int tid = threadIdx.x;
  const int w = tid >> 6, l = tid & 63;
  const int lan = l & 31;
  const int dl = lan >> 2, g = lan & 3;
  const int bid = blockIdx.x;
  const bool isB1 = bid < 64;
  const int J = bid & 63;
  const int d = J * 8 + dl;

  // one-time weight staging (coalesced, wave-uniform LDS dest)
  if (isB1) {
    const unsigned short* src = W1p + ((size_t)J << 15) + l * 8;
#pragma unroll
    for (int it = 0; it < 8; ++it) {
      int ch = it * 8 + w;
      gll16(src + ch * 512, Ws + ch * 512);
    }
  } else {
    const unsigned short* src = W2p + ((size_t)J << 16) + l * 8;
#pragma unroll
    for (int it = 0; it < 16; ++it) {
      int ch = it * 8 + w;
      gll16(src + ch * 512, Ws + ch * 512);
    }
  }

  // per-lane constants for the cell epilogue
  float wi0, wi1, wi2, wi3, bs0, bs1, bs2, bs3, wf, bfc0;
  if (isB1) {
    wi0 = Wih1[0 * HD + d]; wi1 = Wih1[1 * HD + d];
    wi2 = Wih1[2 * HD + d]; wi3 = Wih1[3 * HD + d];
    bs0 = bih1[0 * HD + d] + bhh1[0 * HD + d];
    bs1 = bih1[1 * HD + d] + bhh1[1 * HD + d];
    bs2 = bih1[2 * HD + d] + bhh1[2 * HD + d];
    bs3 = bih1[3 * HD + d] + bhh1[3 * HD + d];
    wf = 0.f; bfc0 = 0.f;
  } else {
    wi0 = wi1 = wi2 = wi3 = 0.f;
    bs0 = bih2[0 * HD + d] + bhh2[0 * HD + d];
    bs1 = bih2[1 * HD + d] + bhh2[1 * HD + d];
    bs2 = bih2[2 * HD + d] + bhh2[2 * HD + d];
    bs3 = bih2[3 * HD + d] + bhh2[3 * HD + d];
    wf = wfc[d]; bfc0 = bfc[0];
  }
  __syncthreads();                          // drains gll16 too

  unsigned bar = 0;
  for (int t = 0; t < TTOT; ++t) {
    const int p = t & 1;
    if (isB1) {
      // ---------------- phase A: layer-1 ----------------
      const unsigned short* hpH = h1H + p * HE + l * 8;
      const unsigned short* hpL = h1L + p * HE + l * 8;
      unsigned short* hoH = h1H + (p ^ 1) * HE;
      unsigned short* hoL = h1L + (p ^ 1) * HE;
#pragma unroll
      for (int it = 0; it < 2; ++it) {
        const int nt = w * 2 + it;
        const unsigned short* aH = hpH + nt * 16384;
        const unsigned short* aL = hpL + nt * 16384;
        f32x16 acc;
#pragma unroll
        for (int r = 0; r < 16; ++r) acc[r] = 0.f;
#pragma unroll
        for (int cks = 0; cks < 32; ++cks) {
          short8 ah = *(const short8*)(aH + cks * 512);
          short8 al = *(const short8*)(aL + cks * 512);
          const short* bp = (const short*)Ws + cks * 512 + l * 8;
          short8 bh = *(const short8*)bp;
          short8 bl = *(const short8*)(bp + 16384);
          acc = __builtin_amdgcn_mfma_f32_32x32x16_bf16(ah, bh, acc, 0, 0, 0);
          acc = __builtin_amdgcn_mfma_f32_32x32x16_bf16(ah, bl, acc, 0, 0, 0);
          acc = __builtin_amdgcn_mfma_f32_32x32x16_bf16(al, bh, acc, 0, 0, 0);
        }
#pragma unroll
        for (int r = 0; r < 16; ++r) {
          float v  = acc[r];
          float x1 = __shfl_xor(v, 1);
          float ev = (g & 1) ? x1 : v;
          float ov = (g & 1) ? v : x1;
          float ev2 = __shfl_xor(ev, 2);
          float ov2 = __shfl_xor(ov, 2);
          float vi = (g & 2) ? ev2 : ev;
          float vf = (g & 2) ? ov2 : ov;
          float vg = (g & 2) ? ev : ev2;
          float vo = (g & 2) ? ov : ov2;
          int nrow = (r & 3) + 8 * (r >> 2) + 4 * (l >> 5);
          int n = nt * 32 + nrow;
          if (g == 0) {
            float xv;
            if (t < TENC) xv = x[n * TENC + t];
            else {
              int j2 = t - TENC;
              xv = (tfm[j2] > 0) ? tgt[n * FDEC + j2] : outp[n * TTOT + t - 1];
            }
            float pi = vi + xv * wi0 + bs0;
            float pf = vf + xv * wi1 + bs1;
            float pg = vg + xv * wi2 + bs2;
            float po = vo + xv * wi3 + bs3;
            float ig = 1.f / (1.f + expf(-pi));
            float fg = 1.f / (1.f + expf(-pf));
            float gv = tanhf(pg);
            float og = 1.f / (1.f + expf(-po));
            float* cp = c1 + (((size_t)J) << 12) + n * 8 + dl;
            float cn = fg * (*cp) + ig * gv;
            *cp = cn;
            float h = og * tanhf(cn);
            unsigned short hh = f2bf(h);
            size_t pix = hpk(n, d);
            hoH[pix] = hh;
            hoL[pix] = f2bf(h - bf2f(hh));
          }
        }
      }
    }
    bar += NBLK; gridbar(cnt, bar);
    if (!isB1) {
      // ---------------- phase B: layer-2 + FC ----------------
      const unsigned short* a1Hb = h1H + (p ^ 1) * HE + l * 8;
      const unsigned short* a1Lb = h1L + (p ^ 1) * HE + l * 8;
      const unsigned short* a2Hb = h2H + p * HE + l * 8;
      const unsigned short* a2Lb = h2L + p * HE + l * 8;
      unsigned short* hoH = h2H + (p ^ 1) * HE;
      unsigned short* hoL = h2L + (p ^ 1) * HE;
#pragma unroll
      for (int it = 0; it < 2; ++it) {
        const int nt = w * 2 + it;
        const unsigned short* b1H = a1Hb + nt * 16384;
        const unsigned short* b1L = a1Lb + nt * 16384;
        const unsigned short* b2H = a2Hb + nt * 16384;
        const unsigned short* b2L = a2Lb + nt * 16384;
        f32x16 acc;
#pragma unroll
        for (int r = 0; r < 16; ++r) acc[r] = 0.f;
#pragma unroll
        for (int cks = 0; cks < 32; ++cks) {
          short8 ah = *(const short8*)(b1H + cks * 512);
          short8 al = *(const short8*)(b1L + cks * 512);
          const short* bp = (const short*)Ws + cks * 512 + l * 8;
          short8 bh = *(const short8*)bp;
          short8 bl = *(const short8*)(bp + 32768);
          acc = __builtin_amdgcn_mfma_f32_32x32x16_bf16(ah, bh, acc, 0, 0, 0);
          acc = __builtin_amdgcn_mfma_f32_32x32x16_bf16(ah, bl, acc, 0, 0, 0);
          acc = __builtin_amdgcn_mfma_f32_32x32x16_bf16(al, bh, acc, 0, 0, 0);
        }
#pragma unroll
        for (int cks = 0; cks < 32; ++cks) {
          short8 ah = *(const short8*)(b2H + cks * 512);
          short8 al = *(const short8*)(b2L + cks * 512);
          const short* bp = (const short*)Ws + (cks + 32) * 512 + l * 8;
          short8 bh = *(const short8*)bp;
          short8 bl = *(const short8*)(bp + 32768);
          acc = __builtin_amdgcn_mfma_f32_32x32x16_bf16(ah, bh, acc, 0, 0, 0);
          acc = __builtin_amdgcn_mfma_f32_32x32x16_bf16(ah, bl, acc, 0, 0, 0);
          acc = __builtin_amdgcn_mfma_f32_32x32x16_bf16(al, bh, acc, 0, 0, 0);
        }
#pragma unroll
        for (int r = 0; r < 16; ++r) {
          float v  = acc[r];
          float x1 = __shfl_xor(v, 1);
          float ev = (g & 1) ? x1 : v;
          float ov = (g & 1) ? v : x1;
          float ev2 = __shfl_xor(ev, 2);
          float ov2 = __shfl_xor(ov, 2);
          float vi = (g & 2) ? ev2 : ev;
          float vf = (g & 2) ? ov2 : ov;
          float vg = (g & 2) ? ev : ev2;
          float vo = (g & 2) ? ov : ov2;
          int nrow = (r & 3) + 8 * (r >> 2) + 4 * (l >> 5);
          int n = nt * 32 + nrow;
          float pp = 0.f;
          if (g == 0) {
            float pi = vi + bs0;
            float pf = vf + bs1;
            float pg = vg + bs2;
            float po = vo + bs3;
            float ig = 1.f / (1.f + expf(-pi));
            float fg = 1.f / (1.f + expf(-pf));
            float gv = tanhf(pg);
            float og = 1.f / (1.f + expf(-po));
            float* cp = c2 + (((size_t)J) << 12) + n * 8 + dl;
            float cn = fg * (*cp) + ig * gv;
            *cp = cn;
            float h = og * tanhf(cn);
            unsigned short hh = f2bf(h);
            size_t pix = hpk(n, d);
            hoH[pix] = hh;
            hoL[pix] = f2bf(h - bf2f(hh));
            pp = h * wf;
          }
          pp += __shfl_xor(pp, 1);
          pp += __shfl_xor(pp, 2);
          pp += __shfl_xor(pp, 4);
          pp += __shfl_xor(pp, 8);
          pp += __shfl_xor(pp, 16);
          if (lan == 0)
            atomicAdd(&outp[n * TTOT + t], pp + (J == 0 ? bfc0 : 0.f));
        }
      }
    }
    bar += NBLK; gridbar(cnt, bar);
  }
}

// ---------------------------------------------------------------------------
extern "C" void kernel_launch(void* const* d_in, const int* in_sizes, int n_in,
                              void* d_out, int out_size, void* d_ws, size_t ws_size,
                              hipStream_t stream)
{
  const float* x    = (const float*)d_in[0];
  const float* tgt  = (const float*)d_in[1];
  const int*   tfm  = (const int*)  d_in[2];
  const float* Wih1 = (const float*)d_in[4];
  const float* Whh1 = (const float*)d_in[5];
  const float* bih1 = (const float*)d_in[6];
  const float* bhh1 = (const float*)d_in[7];
  const float* Wih2 = (const float*)d_in[8];
  const float* Whh2 = (const float*)d_in[9];
  const float* bih2 = (const float*)d_in[10];
  const float* bhh2 = (const float*)d_in[11];
  const float* wfc  = (const float*)d_in[12];
  const float* bfc  = (const float*)d_in[13];
  float* outp = (float*)d_out;

  unsigned short* ws16 = (unsigned short*)d_ws;
  unsigned short* W1p = ws16;                        // 2,097,152 shorts (4 MB)
  unsigned short* W2p = ws16 + 2097152;              // 4,194,304 shorts (8 MB)
  unsigned short* h1H = ws16 + 6291456;              // 2*HE each
  unsigned short* h1L = h1H + 2 * HE;
  unsigned short* h2H = h1L + 2 * HE;
  unsigned short* h2L = h2H + 2 * HE;
  float* c1 = (float*)(h2L + 2 * HE);                // 262144 floats
  float* c2 = c1 + 262144;
  unsigned* cnt = (unsigned*)(c2 + 262144);

  // zero h (both parities), c, and the barrier counter
  hipMemsetAsync(h1H, 0,
      (size_t)8 * HE * sizeof(unsigned short) + (size_t)2 * 262144 * sizeof(float) + 64,
      stream);
  hipMemsetAsync(d_out, 0, (size_t)NB * TTOT * sizeof(float), stream);

  split_w<<<1536, 256, 0, stream>>>(Whh1, Wih2, Whh2, W1p, W2p);

  lstm_persist<<<dim3(NBLK), dim3(512), 0, stream>>>(
      h1H, h1L, h2H, h2L, c1, c2, W1p, W2p,
      Wih1, bih1, bhh1, bih2, bhh2,
      x, tgt, tfm, wfc, bfc, outp, cnt);
}

// Round 11
// 4024.229 us; speedup vs baseline: 12.3850x; 12.3850x over previous
//
#include <hip/hip_runtime.h>
#include <math.h>

#define NB   512
#define TENC 128
#define FDEC 32
#define TTOT 160
#define HD   512
#define HE   262144          // shorts per h buffer (512n x 512d)

typedef short  short8  __attribute__((ext_vector_type(8)));
typedef float  f32x16  __attribute__((ext_vector_type(16)));

#define MFMA32 __builtin_amdgcn_mfma_f32_32x32x16_bf16

__device__ __forceinline__ unsigned short f2bf(float f) {
  unsigned u = __float_as_uint(f);
  u += 0x7FFFu + ((u >> 16) & 1u);          // RNE
  return (unsigned short)(u >> 16);
}
__device__ __forceinline__ float bf2f(unsigned short h) {
  return __uint_as_float(((unsigned)h) << 16);
}
__device__ __forceinline__ void gll16(const void* g, void* l) {
  __builtin_amdgcn_global_load_lds(
      (const __attribute__((address_space(1))) void*)g,
      (__attribute__((address_space(3))) void*)l, 16, 0, 0);
}

// packed-h short index for element (n, d): 32-row n-blocks, fragment-major.
__device__ __forceinline__ size_t hpk(int n, int d) {
  int nblk = n >> 5, lanw = n & 31;
  int cks = d >> 4, kq = (d >> 3) & 1;
  return (size_t)nblk * 16384 +
         (size_t)((((cks * 64 + kq * 32 + lanw) << 3) + (d & 7)));
}

// ---------------------------------------------------------------------------
// Pre-pack weights fragment-major (round-9 layout, verified):
// W1p: 32 J-blocks(64 j) x [hi 4096 u | lo 4096 u], u = cks*128 + kgrp*64 + jl
// W2p: 64 J-blocks(32 j) x [hi | lo],               u = cks*64  + kgrp*32 + jl
// ---------------------------------------------------------------------------
__global__ __launch_bounds__(256) void split_w(
    const float* __restrict__ Whh1, const float* __restrict__ Wih2,
    const float* __restrict__ Whh2,
    unsigned short* __restrict__ W1p, unsigned short* __restrict__ W2p)
{
  int idx = blockIdx.x * 256 + threadIdx.x;
  if (idx < 131072) {
    int J = idx >> 12, u = idx & 4095;
    int cks = u >> 7, kgrp = (u >> 6) & 1, jl = u & 63;
    int j = J * 64 + jl;
    int k = cks * 16 + kgrp * 8;
    int g = j & 3, d = j >> 2;
    const float* s = Whh1 + (size_t)(g * HD + d) * HD + k;
    unsigned short* oh = W1p + ((size_t)J << 16) + (size_t)u * 8;
    unsigned short* ol = oh + 32768;
#pragma unroll
    for (int i = 0; i < 8; ++i) {
      float v = s[i];
      unsigned short h = f2bf(v);
      oh[i] = h; ol[i] = f2bf(v - bf2f(h));
    }
  } else {
    int q2 = idx - 131072;
    int J = q2 >> 12, u = q2 & 4095;
    int cks = u >> 6, kgrp = (u >> 5) & 1, jl = u & 31;
    int j = J * 32 + jl;
    int k = cks * 16 + kgrp * 8;
    int g = j & 3, d = j >> 2;
    const float* s = (k < 512) ? Wih2 + (size_t)(g * HD + d) * HD + k
                               : Whh2 + (size_t)(g * HD + d) * HD + (k - 512);
    unsigned short* oh = W2p + ((size_t)J << 16) + (size_t)u * 8;
    unsigned short* ol = oh + 32768;
#pragma unroll
    for (int i = 0; i < 8; ++i) {
      float v = s[i];
      unsigned short h = f2bf(v);
      oh[i] = h; ol[i] = f2bf(v - bf2f(h));
    }
  }
}

// stage one phase (half) of the 128KB W slice: 8 gll16 per wave.
// segs (512 shorts each): {s0, s0+8, s0+32, s0+40} + lo(+64), s0 = ph*16 + w.
// Covers W k-chunks {first half of each wave-K-range} (ph0) / second (ph1).
__device__ __forceinline__ void stage_phase(unsigned short* Ws,
    const unsigned short* wsrcl, int w, int phase) {
  int s0 = phase * 16 + w;
#pragma unroll
  for (int q = 0; q < 4; ++q) {
    int s = s0 + (q & 1) * 8 + (q >> 1) * 32;
    gll16(wsrcl + (size_t)s * 512, Ws + (size_t)s * 512);
    gll16(wsrcl + (size_t)(s + 64) * 512, Ws + (size_t)(s + 64) * 512);
  }
}

// ---------------------------------------------------------------------------
// Layer-1 body. Tile 64j x 64n, 8 waves = (kh, jh, nh). 256 blocks (J,ny).
// ---------------------------------------------------------------------------
__device__ __forceinline__ void run_l1(
    unsigned short* h1H, unsigned short* h1L, float* c1,
    const unsigned short* W1p, const float* Wih,
    const float* bih, const float* bhh,
    const float* x, const float* tgt, const int* tfm,
    const float* outp, int t, int J, int ny, unsigned short* Ws)
{
  const int tid = threadIdx.x;
  const int w = tid >> 6, l = tid & 63;
  const int kh = w >> 2, jh = (w >> 1) & 1, nh = w & 1;
  const int lan = l & 31, kgq = l >> 5;
  const int n0 = ny * 64;
  const int p = t & 1;
  const unsigned short* hinH = h1H + p * HE;
  const unsigned short* hinL = h1L + p * HE;
  unsigned short* houtH = h1H + (p ^ 1) * HE;
  unsigned short* houtL = h1L + (p ^ 1) * HE;

  const unsigned short* wsrcl = W1p + ((size_t)J << 16) + l * 8;
  stage_phase(Ws, wsrcl, w, 0);
  __builtin_amdgcn_sched_barrier(0);

  const unsigned short* aH = hinH + (size_t)(ny * 2 + nh) * 16384 + l * 8 + kh * 8192;
  const unsigned short* aL = hinL + (size_t)(ny * 2 + nh) * 16384 + l * 8 + kh * 8192;

  short8 pH[4], pL[4];
#pragma unroll
  for (int i = 0; i < 4; ++i) {
    pH[i] = *(const short8*)(aH + i * 512);
    pL[i] = *(const short8*)(aL + i * 512);
  }
  __builtin_amdgcn_sched_barrier(0);
  asm volatile("s_waitcnt vmcnt(8)" ::: "memory");   // ph0 W in LDS
  __builtin_amdgcn_s_barrier();
  __builtin_amdgcn_sched_barrier(0);

  f32x16 acc;
#pragma unroll
  for (int r = 0; r < 16; ++r) acc[r] = 0.f;

#pragma unroll
  for (int u = 0; u < 16; ++u) {
    if (u == 4) {                                    // issue ph1 mid-loop
      stage_phase(Ws, wsrcl, w, 1);
      __builtin_amdgcn_sched_barrier(0);
    }
    if (u == 8) {                                    // ph1 ready (A(8..11)=8 out)
      asm volatile("s_waitcnt vmcnt(8)" ::: "memory");
      __builtin_amdgcn_s_barrier();
      __builtin_amdgcn_sched_barrier(0);
    }
    short8 ah = pH[u & 3], al = pL[u & 3];
    if (u < 12) {
      pH[u & 3] = *(const short8*)(aH + (u + 4) * 512);
      pL[u & 3] = *(const short8*)(aL + (u + 4) * 512);
    }
    int ub = ((kh * 16 + u) * 128 + kgq * 64 + jh * 32 + lan) * 8;
    const short* bp = (const short*)Ws;
    short8 bh = *(const short8*)(bp + ub);
    short8 bl = *(const short8*)(bp + ub + 32768);
    acc = MFMA32(ah, bh, acc, 0, 0, 0);
    acc = MFMA32(ah, bl, acc, 0, 0, 0);
    acc = MFMA32(al, bh, acc, 0, 0, 0);
  }

  __syncthreads();
  float* Gs = (float*)Ws;                  // [128 rows (kh,jl)][66]
#pragma unroll
  for (int r = 0; r < 16; ++r) {
    int nrow = (r & 3) + 8 * (r >> 2) + 4 * kgq;
    Gs[(kh * 64 + jh * 32 + lan) * 66 + nh * 32 + nrow] = acc[r];
  }
  __syncthreads();

  const int dl = tid & 15, q = tid >> 4;
  const int dg = J * 16 + dl;
  float wi[4], bsum[4];
#pragma unroll
  for (int g4 = 0; g4 < 4; ++g4) {
    int row = g4 * HD + dg;
    wi[g4] = Wih[row];
    bsum[g4] = bih[row] + bhh[row];
  }
#pragma unroll
  for (int s = 0; s < 2; ++s) {
    int nloc = q * 2 + s, n = n0 + nloc;
    float xv;
    if (t < TENC) xv = x[n * TENC + t];
    else {
      int j2 = t - TENC;
      xv = (tfm[j2] > 0) ? tgt[n * FDEC + j2] : outp[n * TTOT + t - 1];
    }
    float pg4[4];
#pragma unroll
    for (int g4 = 0; g4 < 4; ++g4)
      pg4[g4] = Gs[(dl * 4 + g4) * 66 + nloc] + Gs[(64 + dl * 4 + g4) * 66 + nloc]
              + xv * wi[g4] + bsum[g4];
    float ig = 1.f / (1.f + expf(-pg4[0]));
    float fg = 1.f / (1.f + expf(-pg4[1]));
    float gv = tanhf(pg4[2]);
    float og = 1.f / (1.f + expf(-pg4[3]));
    int idx = n * HD + dg;
    float c = fg * c1[idx] + ig * gv;
    c1[idx] = c;
    float h = og * tanhf(c);
    unsigned short hh = f2bf(h);
    size_t pi = hpk(n, dg);
    houtH[pi] = hh;
    houtL[pi] = f2bf(h - bf2f(hh));
  }
}

// ---------------------------------------------------------------------------
// Layer-2 body (step s). Tile 32j x 128n, 8 waves = (kh: h1|h2, nq).
// ---------------------------------------------------------------------------
__device__ __forceinline__ void run_l2(
    unsigned short* h1H, unsigned short* h1L,
    unsigned short* h2H, unsigned short* h2L, float* c2,
    const unsigned short* W2p,
    const float* bih, const float* bhh,
    const float* wfc, const float* bfc,
    float* outp, int s, int J, int ny, unsigned short* Ws)
{
  const int tid = threadIdx.x;
  const int w = tid >> 6, l = tid & 63;
  const int kh = w >> 2, nq = w & 3;
  const int lan = l & 31, kgq = l >> 5;
  const int n0 = ny * 128;
  const int ps = s & 1;
  const unsigned short* a1H = h1H + (ps ^ 1) * HE;   // h1(s)
  const unsigned short* a1L = h1L + (ps ^ 1) * HE;
  const unsigned short* a2H = h2H + ps * HE;         // h2(s-1)
  const unsigned short* a2L = h2L + ps * HE;
  unsigned short* houtH = h2H + (ps ^ 1) * HE;
  unsigned short* houtL = h2L + (ps ^ 1) * HE;

  const unsigned short* wsrcl = W2p + ((size_t)J << 16) + l * 8;
  stage_phase(Ws, wsrcl, w, 0);
  __builtin_amdgcn_sched_barrier(0);

  const unsigned short* aH = (kh ? a2H : a1H) + (size_t)(ny * 4 + nq) * 16384 + l * 8;
  const unsigned short* aL = (kh ? a2L : a1L) + (size_t)(ny * 4 + nq) * 16384 + l * 8;

  short8 pH[4], pL[4];
#pragma unroll
  for (int i = 0; i < 4; ++i) {
    pH[i] = *(const short8*)(aH + i * 512);
    pL[i] = *(const short8*)(aL + i * 512);
  }
  __builtin_amdgcn_sched_barrier(0);
  asm volatile("s_waitcnt vmcnt(8)" ::: "memory");   // ph0 W in LDS
  __builtin_amdgcn_s_barrier();
  __builtin_amdgcn_sched_barrier(0);

  f32x16 acc;
#pragma unroll
  for (int r = 0; r < 16; ++r) acc[r] = 0.f;

#pragma unroll
  for (int u = 0; u < 32; ++u) {
    if (u == 12) {
      stage_phase(Ws, wsrcl, w, 1);
      __builtin_amdgcn_sched_barrier(0);
    }
    if (u == 16) {                                   // A(16..19)=8 outstanding
      asm volatile("s_waitcnt vmcnt(8)" ::: "memory");
      __builtin_amdgcn_s_barrier();
      __builtin_amdgcn_sched_barrier(0);
    }
    short8 ah = pH[u & 3], al = pL[u & 3];
    if (u < 28) {
      pH[u & 3] = *(const short8*)(aH + (u + 4) * 512);
      pL[u & 3] = *(const short8*)(aL + (u + 4) * 512);
    }
    int ub = ((kh * 32 + u) * 64 + kgq * 32 + lan) * 8;
    const short* bp = (const short*)Ws;
    short8 bh = *(const short8*)(bp + ub);
    short8 bl = *(const short8*)(bp + ub + 32768);
    acc = MFMA32(ah, bh, acc, 0, 0, 0);
    acc = MFMA32(ah, bl, acc, 0, 0, 0);
    acc = MFMA32(al, bh, acc, 0, 0, 0);
  }

  __syncthreads();
  float* Gs = (float*)Ws;                  // [64 rows (kh,jl)][130]
  float* Rd = (float*)Ws + 64 * 130;       // [128][9]
#pragma unroll
  for (int r = 0; r < 16; ++r) {
    int nrow = (r & 3) + 8 * (r >> 2) + 4 * kgq;
    Gs[(kh * 32 + lan) * 130 + nq * 32 + nrow] = acc[r];
  }
  __syncthreads();

  const int dl = tid & 7, q = tid >> 3;
  const int dg = J * 8 + dl;
  float bsum[4];
#pragma unroll
  for (int g4 = 0; g4 < 4; ++g4) bsum[g4] = bih[g4 * HD + dg] + bhh[g4 * HD + dg];
  const float wf = wfc[dg];
#pragma unroll
  for (int s2 = 0; s2 < 2; ++s2) {
    int nloc = q * 2 + s2, n = n0 + nloc;
    float pg4[4];
#pragma unroll
    for (int g4 = 0; g4 < 4; ++g4)
      pg4[g4] = Gs[(dl * 4 + g4) * 130 + nloc] + Gs[(32 + dl * 4 + g4) * 130 + nloc]
              + bsum[g4];
    float ig = 1.f / (1.f + expf(-pg4[0]));
    float fg = 1.f / (1.f + expf(-pg4[1]));
    float gv = tanhf(pg4[2]);
    float og = 1.f / (1.f + expf(-pg4[3]));
    int idx = n * HD + dg;
    float c = fg * c2[idx] + ig * gv;
    c2[idx] = c;
    float h = og * tanhf(c);
    unsigned short hh = f2bf(h);
    size_t pi = hpk(n, dg);
    houtH[pi] = hh;
    houtL[pi] = f2bf(h - bf2f(hh));
    Rd[nloc * 9 + dl] = h * wf;
  }
  __syncthreads();
  if (tid < 128) {
    float sum = 0.f;
#pragma unroll
    for (int k = 0; k < 8; ++k) sum += Rd[tid * 9 + k];
    if (J == 0) sum += bfc[0];
    atomicAdd(&outp[(n0 + tid) * TTOT + s], sum);
  }
}

// ---------------------------------------------------------------------------
__global__ __launch_bounds__(512, 2) void l1_step(
    unsigned short* h1H, unsigned short* h1L, float* c1,
    const unsigned short* W1p, const float* Wih,
    const float* bih, const float* bhh,
    const float* x, const float* tgt, const int* tfm,
    const float* outp, int t)
{
  __shared__ unsigned short Ws[65536];
  run_l1(h1H, h1L, c1, W1p, Wih, bih, bhh, x, tgt, tfm, outp,
         t, blockIdx.x >> 3, blockIdx.x & 7, Ws);
}

__global__ __launch_bounds__(512, 2) void l2_step(
    unsigned short* h1H, unsigned short* h1L,
    unsigned short* h2H, unsigned short* h2L, float* c2,
    const unsigned short* W2p,
    const float* bih, const float* bhh,
    const float* wfc, const float* bfc, float* outp, int s)
{
  __shared__ unsigned short Ws[65536];
  run_l2(h1H, h1L, h2H, h2L, c2, W2p, bih, bhh, wfc, bfc, outp,
         s, blockIdx.x >> 2, blockIdx.x & 3, Ws);
}

// merged encoder launch: blocks 0..255 run L1(t); 256..511 run L2(t-1).
__global__ __launch_bounds__(512, 2) void enc_step(
    unsigned short* h1H, unsigned short* h1L,
    unsigned short* h2H, unsigned short* h2L,
    float* c1, float* c2,
    const unsigned short* W1p, const unsigned short* W2p,
    const float* Wih1, const float* bih1, const float* bhh1,
    const float* bih2, const float* bhh2,
    const float* x, const float* tgt, const int* tfm,
    const float* wfc, const float* bfc, float* outp, int t)
{
  __shared__ unsigned short Ws[65536];
  int bx = blockIdx.x;
  if (bx < 256) {
    run_l1(h1H, h1L, c1, W1p, Wih1, bih1, bhh1, x, tgt, tfm, outp,
           t, bx >> 3, bx & 7, Ws);
  } else {
    int b2 = bx - 256;
    run_l2(h1H, h1L, h2H, h2L, c2, W2p, bih2, bhh2, wfc, bfc, outp,
           t - 1, b2 >> 2, b2 & 3, Ws);
  }
}

// ---------------------------------------------------------------------------
extern "C" void kernel_launch(void* const* d_in, const int* in_sizes, int n_in,
                              void* d_out, int out_size, void* d_ws, size_t ws_size,
                              hipStream_t stream)
{
  const float* x    = (const float*)d_in[0];
  const float* tgt  = (const float*)d_in[1];
  const int*   tfm  = (const int*)  d_in[2];
  const float* Wih1 = (const float*)d_in[4];
  const float* Whh1 = (const float*)d_in[5];
  const float* bih1 = (const float*)d_in[6];
  const float* bhh1 = (const float*)d_in[7];
  const float* Wih2 = (const float*)d_in[8];
  const float* Whh2 = (const float*)d_in[9];
  const float* bih2 = (const float*)d_in[10];
  const float* bhh2 = (const float*)d_in[11];
  const float* wfc  = (const float*)d_in[12];
  const float* bfc  = (const float*)d_in[13];
  float* outp = (float*)d_out;

  unsigned short* ws16 = (unsigned short*)d_ws;
  unsigned short* W1p = ws16;                        // 32*65536 shorts (4 MB)
  unsigned short* W2p = ws16 + 2097152;              // 64*65536 shorts (8 MB)
  unsigned short* h1H = ws16 + 6291456;              // [2][HE] each, packed
  unsigned short* h1L = h1H + 2 * HE;
  unsigned short* h2H = h1L + 2 * HE;
  unsigned short* h2L = h2H + 2 * HE;
  float* c1 = (float*)(h2L + 2 * HE);
  float* c2 = c1 + HE;

  hipMemsetAsync(h1H, 0,
      (size_t)8 * HE * sizeof(unsigned short) + (size_t)2 * HE * sizeof(float),
      stream);
  hipMemsetAsync(d_out, 0, (size_t)NB * TTOT * sizeof(float), stream);

  split_w<<<1536, 256, 0, stream>>>(Whh1, Wih2, Whh2, W1p, W2p);

  dim3 blk(512);
  l1_step<<<dim3(256), blk, 0, stream>>>(
      h1H, h1L, c1, W1p, Wih1, bih1, bhh1, x, tgt, tfm, outp, 0);
  for (int i = 1; i < TENC; ++i) {
    enc_step<<<dim3(512), blk, 0, stream>>>(
        h1H, h1L, h2H, h2L, c1, c2, W1p, W2p,
        Wih1, bih1, bhh1, bih2, bhh2, x, tgt, tfm, wfc, bfc, outp, i);
  }
  for (int t = TENC; t < TTOT; ++t) {
    l2_step<<<dim3(256), blk, 0, stream>>>(
        h1H, h1L, h2H, h2L, c2, W2p, bih2, bhh2, wfc, bfc, outp, t - 1);
    l1_step<<<dim3(256), blk, 0, stream>>>(
        h1H, h1L, c1, W1p, Wih1, bih1, bhh1, x, tgt, tfm, outp, t);
  }
  l2_step<<<dim3(256), blk, 0, stream>>>(
      h1H, h1L, h2H, h2L, c2, W2p, bih2, bhh2, wfc, bfc, outp, TTOT - 1);
}